// Round 10
// baseline (226.663 us; speedup 1.0000x reference)
//
#include <hip/hip_runtime.h>
#include <math.h>

#define NB    16        // batch
#define NC    25        // channels
#define HW    65536     // 256*256
#define CHW   (NC * HW)
#define EPSF  1e-8f
#define TPB   256       // 4 waves, 1 px per thread
#define PXB   256       // pixels per block
#define NBLK  (NB * (HW / PXB))   // 4096 blocks
#define NXCD  8
#define CPX   (NBLK / NXCD)       // 512 contiguous logical blocks per XCD
#define NSTR  64        // accumulator stripes (parallel atomic chains)
#define SACC  64        // floats per stripe

__device__ __forceinline__ float wave_reduce(float v) {
#pragma unroll
    for (int o = 32; o > 0; o >>= 1) v += __shfl_down(v, o, 64);
    return v;
}

// R17 = R16 + XCD-aware block swizzle (single-variable change).
// R16 post-mortem: the register pin "landed" (payload likely in unified-file
// AGPRs; VGPR_Count=32) yet dur was IDENTICAL (~75us) -- the 7th structurally
// different kernel to measure 75+/-3us, always with warm(L3)==cold(HBM).
// The only invariant left is the ADDRESS PATTERN: 50 streams strided by
// 256KB. Theory: address-translation serialization (UTCL1 thrash; 3200
// 64KB-pages walked by EVERY XCD under round-robin dispatch). Translation
// latency is identical for L3-hit and HBM-miss data (explains warm==cold),
// has its own tiny outstanding-request budget (explains MLP immunity), and
// no prior change touched the page-touch pattern (explains 7x invariance).
// Fix under test: bid -> (bid%8)*CPX + bid/8 (bijective, 4096%8==0). Each
// XCD then owns 512 CONTIGUOUS blocks = 2 whole images -> UTCL2 working
// set 3200 -> 400 pages (8x), and co-resident CUs share translations.
// There is NO data reuse in this kernel, so this cannot be confounded by
// data-cache locality: any delta is translation reuse.
__global__ __launch_bounds__(TPB) void yolo_main(const float* __restrict__ outputs,
                                                 const float* __restrict__ labels,
                                                 float* __restrict__ acc) {
    const int wv   = threadIdx.x >> 6;
    const int lane = threadIdx.x & 63;
    // XCD swizzle: hardware round-robins consecutive blockIdx across XCDs;
    // give XCD x the contiguous logical range [x*CPX, (x+1)*CPX).
    const int bid  = (blockIdx.x & (NXCD - 1)) * CPX + (blockIdx.x >> 3);
    const int b    = bid >> 8;                      // image
    const int px   = ((bid & 255) << 8) + threadIdx.x;
    const size_t base = (size_t)b * CHW + px;
    const float* op = outputs + base;
    const float* lp = labels  + base;

    // ---- 50 independent coalesced dword loads: the thread's entire input
    float o[NC], l[NC];
#pragma unroll
    for (int c = 0; c < NC; ++c) {
        o[c] = op[(size_t)c * HW];
        l[c] = lp[(size_t)c * HW];
    }
    // single pin point (R16): all o[] live here, no load may cross
    asm volatile("" ::
        "v"(o[0]),  "v"(o[1]),  "v"(o[2]),  "v"(o[3]),  "v"(o[4]),
        "v"(o[5]),  "v"(o[6]),  "v"(o[7]),  "v"(o[8]),  "v"(o[9]),
        "v"(o[10]), "v"(o[11]), "v"(o[12]), "v"(o[13]), "v"(o[14]),
        "v"(o[15]), "v"(o[16]), "v"(o[17]), "v"(o[18]), "v"(o[19]),
        "v"(o[20]), "v"(o[21]), "v"(o[22]), "v"(o[23]), "v"(o[24])
        : "memory");

    // ---- channel 0: BCE + F1 counters
    const float xv = o[0], yv = l[0];
    float xc = fminf(fmaxf(xv,        EPSF), 1.0f - EPSF);
    float x1 = fminf(fmaxf(1.0f - xv, EPSF), 1.0f - EPSF);
    float obj = -yv * (1.0f - xc) * __logf(xc)
                - (1.0f - yv) * (1.0f - x1) * __logf(x1);
    const float p  = (xv > 0.5f) ? 1.f : 0.f;
    const float yt = (yv > 0.5f) ? 1.f : 0.f;
    float tp = p * yt;
    float fp = p * (1.f - yt);
    float fn = (1.f - p) * yt;

    // ---- channels 1..4: size / offset L1 (weighted by y)
    float szs  = yv * (fabsf(o[1] - l[1]) + fabsf(o[2] - l[2]));
    float offs = yv * (fabsf(o[3] - l[3]) + fabsf(o[4] - l[4]));

    // ---- channels 5..24: argmax(labels) carrying outputs
    // ascending c + strict '>' = argmax first-index tie-break
    float vmax = -1.0f, vout = 0.0f;
#pragma unroll
    for (int c = 5; c < NC; ++c) {
        if (l[c] > vmax) { vmax = l[c]; vout = o[c]; }
    }
    float cls = yv * (-vout);

    // ---- block reduction: 7 values
    obj  = wave_reduce(obj);
    szs  = wave_reduce(szs);
    offs = wave_reduce(offs);
    cls  = wave_reduce(cls);
    tp   = wave_reduce(tp);
    fp   = wave_reduce(fp);
    fn   = wave_reduce(fn);

    __shared__ float sm[TPB / 64][7];
    if (lane == 0) {
        sm[wv][0] = obj;  sm[wv][1] = szs; sm[wv][2] = offs;
        sm[wv][3] = cls;  sm[wv][4] = tp;  sm[wv][5] = fp;  sm[wv][6] = fn;
    }
    __syncthreads();
    if (threadIdx.x < 7) {
        float s = 0.f;
#pragma unroll
        for (int w = 0; w < TPB / 64; ++w) s += sm[w][threadIdx.x];
        // striped accumulators: 64 parallel short atomic chains
        float* st = acc + (size_t)(bid & (NSTR - 1)) * SACC;
        if (threadIdx.x < 4) atomicAdd(st + threadIdx.x, s);
        else                 atomicAdd(st + 4 + 3 * b + (threadIdx.x - 4), s);
    }
}

__global__ void yolo_fin(const float* __restrict__ acc, float* __restrict__ out) {
    const int t = threadIdx.x;                // 64 threads, 1 wave
    __shared__ float fin[52];
    if (t < 52) {
        float s = 0.f;
#pragma unroll
        for (int st = 0; st < NSTR; ++st) s += acc[st * SACC + t];
        fin[t] = s;
    }
    __syncthreads();
    if (t == 0) {
        float objT = fin[0];
        float szT  = 0.1f * fin[1];
        float offT = 0.1f * fin[2];
        float clsT = fin[3];
        float f1 = 0.f;
        for (int bb = 0; bb < NB; ++bb) {
            float tpv = fin[4 + 3 * bb], fpv = fin[5 + 3 * bb], fnv = fin[6 + 3 * bb];
            float den = 2.f * tpv + fpv + fnv;
            f1 += (den > 0.f) ? (2.f * tpv) / fmaxf(den, 1.f) : 0.f;
        }
        f1 *= (1.0f / NB);
        out[0] = objT + szT + offT + clsT;
        out[1] = f1;
        out[2] = objT;
        out[3] = szT;
        out[4] = offT;
        out[5] = clsT;
    }
}

extern "C" void kernel_launch(void* const* d_in, const int* in_sizes, int n_in,
                              void* d_out, int out_size, void* d_ws, size_t ws_size,
                              hipStream_t stream) {
    const float* outputs = (const float*)d_in[0];
    const float* labels  = (const float*)d_in[1];
    float* acc = (float*)d_ws;   // 64 stripes x 64 floats = 16 KB

    hipMemsetAsync(acc, 0, NSTR * SACC * sizeof(float), stream);
    yolo_main<<<NBLK, TPB, 0, stream>>>(outputs, labels, acc);
    yolo_fin<<<1, 64, 0, stream>>>(acc, (float*)d_out);
}

// Round 11
// 221.679 us; speedup vs baseline: 1.0225x; 1.0225x over previous
//
#include <hip/hip_runtime.h>
#include <math.h>

#define NB    16        // batch
#define NC    25        // channels
#define HW    65536     // 256*256
#define CHW   (NC * HW)
#define EPSF  1e-8f
#define TPB   256       // 4 waves, 1 px per thread
#define PXB   256       // pixels per block
#define NBLK  (NB * (HW / PXB))   // 4096 blocks
#define NSTR  64        // accumulator stripes (parallel atomic chains)
#define SACC  64        // floats per stripe

__device__ __forceinline__ float wave_reduce(float v) {
#pragma unroll
    for (int o = 32; o > 0; o >>= 1) v += __shfl_down(v, o, 64);
    return v;
}

// R18: inline-asm loads -- the compiler-proof MLP experiment.
// Model that fits all 8 prior rounds: ~2 outstanding loads/wave (every
// VGPR readback proves the payload is never simultaneously live; R16's
// "pin" gave VGPR=32, i.e. it silently failed) x ~900cy loaded latency,
// hidden only by ~21 waves/CU: 64 waves x 50 loads x 900cy / 21 = ~60-75us.
// Explains warm(L3)==cold(HBM) (L3 hit ~ full round trip), and why
// occupancy/atomic/bank/swizzle changes did nothing. Source-level fixes
// all failed: scheduler sinks (R9), regalloc spills (R10), IR sinks past
// sched_barrier (R13), per-value asm serializes (R15), one-point pin
// ignored (R16), XCD swizzle regressed (R17, reverted).
// Fix: issue all 50 loads as volatile inline asm (fixed mutual order, no
// compiler waitcnt between them, outputs are real live defs), then ONE
// s_waitcnt vmcnt(0), then sched_barrier(0) (rule #18: stops consumers
// hoisting past an asm waitcnt), then consume. saddr form: SGPR base +
// 32-bit byte offset stepped by 256KB (fits: max offset 105MB < 2^31).
// Emitted code MUST hold 50 outstanding loads -> 12.8KB in flight/wave
// x ~16 waves/CU = 200KB/CU vs ~22KB Little's-law target.
__global__ __launch_bounds__(TPB) void yolo_main(const float* __restrict__ outputs,
                                                 const float* __restrict__ labels,
                                                 float* __restrict__ acc) {
    const int wv   = threadIdx.x >> 6;
    const int lane = threadIdx.x & 63;
    const int b    = blockIdx.x >> 8;                      // image
    const int px   = ((blockIdx.x & 255) << 8) + threadIdx.x;

    // byte offset of this thread's channel-0 element (same for both tensors)
    unsigned voff = (unsigned)(((size_t)b * CHW + px) * sizeof(float));

    // ---- 50 loads issued back-to-back, zero compiler interference
    float o[NC], l[NC];
#pragma unroll
    for (int c = 0; c < NC; ++c) {
        asm volatile("global_load_dword %0, %1, %2"
                     : "=v"(o[c]) : "v"(voff), "s"(outputs));
        asm volatile("global_load_dword %0, %1, %2"
                     : "=v"(l[c]) : "v"(voff), "s"(labels));
        voff += HW * sizeof(float);          // next channel plane (+256KB)
    }
    asm volatile("s_waitcnt vmcnt(0)" ::: "memory");
    __builtin_amdgcn_sched_barrier(0);       // rule #18: no hoist past the wait

    // ---- channel 0: BCE + F1 counters
    const float xv = o[0], yv = l[0];
    float xc = fminf(fmaxf(xv,        EPSF), 1.0f - EPSF);
    float x1 = fminf(fmaxf(1.0f - xv, EPSF), 1.0f - EPSF);
    float obj = -yv * (1.0f - xc) * __logf(xc)
                - (1.0f - yv) * (1.0f - x1) * __logf(x1);
    const float p  = (xv > 0.5f) ? 1.f : 0.f;
    const float yt = (yv > 0.5f) ? 1.f : 0.f;
    float tp = p * yt;
    float fp = p * (1.f - yt);
    float fn = (1.f - p) * yt;

    // ---- channels 1..4: size / offset L1 (weighted by y)
    float szs  = yv * (fabsf(o[1] - l[1]) + fabsf(o[2] - l[2]));
    float offs = yv * (fabsf(o[3] - l[3]) + fabsf(o[4] - l[4]));

    // ---- channels 5..24: argmax(labels) carrying outputs
    // ascending c + strict '>' = argmax first-index tie-break
    float vmax = -1.0f, vout = 0.0f;
#pragma unroll
    for (int c = 5; c < NC; ++c) {
        if (l[c] > vmax) { vmax = l[c]; vout = o[c]; }
    }
    float cls = yv * (-vout);

    // ---- block reduction: 7 values
    obj  = wave_reduce(obj);
    szs  = wave_reduce(szs);
    offs = wave_reduce(offs);
    cls  = wave_reduce(cls);
    tp   = wave_reduce(tp);
    fp   = wave_reduce(fp);
    fn   = wave_reduce(fn);

    __shared__ float sm[TPB / 64][7];
    if (lane == 0) {
        sm[wv][0] = obj;  sm[wv][1] = szs; sm[wv][2] = offs;
        sm[wv][3] = cls;  sm[wv][4] = tp;  sm[wv][5] = fp;  sm[wv][6] = fn;
    }
    __syncthreads();
    if (threadIdx.x < 7) {
        float s = 0.f;
#pragma unroll
        for (int w = 0; w < TPB / 64; ++w) s += sm[w][threadIdx.x];
        // striped accumulators: 64 parallel short atomic chains (R13 win)
        float* st = acc + (size_t)(blockIdx.x & (NSTR - 1)) * SACC;
        if (threadIdx.x < 4) atomicAdd(st + threadIdx.x, s);
        else                 atomicAdd(st + 4 + 3 * b + (threadIdx.x - 4), s);
    }
}

__global__ void yolo_fin(const float* __restrict__ acc, float* __restrict__ out) {
    const int t = threadIdx.x;                // 64 threads, 1 wave
    __shared__ float fin[52];
    if (t < 52) {
        float s = 0.f;
#pragma unroll
        for (int st = 0; st < NSTR; ++st) s += acc[st * SACC + t];
        fin[t] = s;
    }
    __syncthreads();
    if (t == 0) {
        float objT = fin[0];
        float szT  = 0.1f * fin[1];
        float offT = 0.1f * fin[2];
        float clsT = fin[3];
        float f1 = 0.f;
        for (int bb = 0; bb < NB; ++bb) {
            float tpv = fin[4 + 3 * bb], fpv = fin[5 + 3 * bb], fnv = fin[6 + 3 * bb];
            float den = 2.f * tpv + fpv + fnv;
            f1 += (den > 0.f) ? (2.f * tpv) / fmaxf(den, 1.f) : 0.f;
        }
        f1 *= (1.0f / NB);
        out[0] = objT + szT + offT + clsT;
        out[1] = f1;
        out[2] = objT;
        out[3] = szT;
        out[4] = offT;
        out[5] = clsT;
    }
}

extern "C" void kernel_launch(void* const* d_in, const int* in_sizes, int n_in,
                              void* d_out, int out_size, void* d_ws, size_t ws_size,
                              hipStream_t stream) {
    const float* outputs = (const float*)d_in[0];
    const float* labels  = (const float*)d_in[1];
    float* acc = (float*)d_ws;   // 64 stripes x 64 floats = 16 KB

    hipMemsetAsync(acc, 0, NSTR * SACC * sizeof(float), stream);
    yolo_main<<<NBLK, TPB, 0, stream>>>(outputs, labels, acc);
    yolo_fin<<<1, 64, 0, stream>>>(acc, (float*)d_out);
}